// Round 2
// baseline (262.744 us; speedup 1.0000x reference)
//
#include <hip/hip_runtime.h>
#include <cstdint>
#include <cstddef>

#define N_ 32
#define C_ 256
#define H_ 56
#define W_ 56

typedef int v4i __attribute__((ext_vector_type(4)));

// ---- workspace layout ----
// sx: padded sign-activations, i8, [n][58 rows][68 w][256 c], chunk-swizzled:
//     16B-chunk ch of position (row,w) lives at slot (ch + w) & 15.
static constexpr size_t SX_BYTES = (size_t)N_ * 58 * 68 * 256;   // 32,309,248
static constexpr size_t WB_OFF   = SX_BYTES;
static constexpr size_t WB_BYTES = 36ull * 16 * 64 * 16;         // 589,824
static constexpr size_t SC_OFF   = WB_OFF + WB_BYTES;            // 256 floats

// ---------------- kernel 0: zero only the halo cells conv reads ----------------
__global__ __launch_bounds__(256) void zero_halo(char* __restrict__ sx) {
    int row = blockIdx.x;      // 0..57
    int n   = blockIdx.y;
    v4i z = {0, 0, 0, 0};
    char* base = sx + ((size_t)n * 58 + row) * (68 * 256);
    if (row == 0 || row == 57) {
        for (int i = threadIdx.x; i < 58 * 16; i += 256)
            *(v4i*)(base + (size_t)i * 16) = z;
    } else {
        int tid = threadIdx.x;
        if (tid < 32) {
            int wpos = (tid >> 4) * 57;       // w = 0 or 57
            int ch   = tid & 15;              // zeros are swizzle-invariant
            *(v4i*)(base + ((size_t)wpos * 16 + ch) * 16) = z;
        }
    }
}

// ---------------- kernel 1: pack x signs -> NHWC i8 (padded, pre-swizzled) ----
__global__ __launch_bounds__(256) void pack_x(const float* __restrict__ x,
                                              char* __restrict__ sx) {
    __shared__ float tile[64 * 65];     // 16.6 KB
    __shared__ char  ob[64 * 256];      // 16 KB packed output tile
    int tid = threadIdx.x;
    int hw0 = blockIdx.x * 64;          // 49 tiles cover 3136 exactly
    int n   = blockIdx.y;

    int cl   = tid >> 6, hwl = tid & 63;
    int hwl2 = tid >> 2, cq  = tid & 3;

    for (int cb = 0; cb < 4; ++cb) {
        const float* xb = x + ((size_t)n * C_ + cb * 64) * 3136 + hw0;
#pragma unroll
        for (int i = 0; i < 16; ++i) {
            int cloc = i * 4 + cl;
            tile[cloc * 65 + hwl] = xb[(size_t)cloc * 3136 + hwl];   // coalesced
        }
        __syncthreads();
        int words[4];
#pragma unroll
        for (int g = 0; g < 4; ++g) {
            int word = 0;
#pragma unroll
            for (int b = 0; b < 4; ++b) {
                float v = tile[(cq * 16 + g * 4 + b) * 65 + hwl2];
                int s = (v > 0.0f) - (v < 0.0f);    // exact sign, 0 at 0
                word |= (s & 0xff) << (8 * b);
            }
            words[g] = word;
        }
        v4i o4 = {words[0], words[1], words[2], words[3]};
        int ch   = cb * 4 + cq;                 // output 16B-chunk index 0..15
        int slot = (ch + hwl2) & 15;            // LDS-side rotation (bank spread)
        *(v4i*)(ob + hwl2 * 256 + slot * 16) = o4;
        __syncthreads();
    }

    // copy-out: contiguous full 256B lines; apply GLOBAL swizzle slot=(ch+wpad)&15
#pragma unroll
    for (int j = 0; j < 4; ++j) {
        int i = tid + j * 256;                  // 0..1023 chunk index in tile
        int hwl3 = i >> 4, ch = i & 15;
        v4i v = *(const v4i*)(ob + hwl3 * 256 + ((ch + hwl3) & 15) * 16);
        int hw = hw0 + hwl3;
        int h = hw / 56, w = hw - h * 56;
        int slot = (ch + (w + 1)) & 15;         // pre-swizzle on padded w index
        *(v4i*)(sx + (((size_t)n * 58 + h + 1) * 68 + (w + 1)) * 256 + slot * 16) = v;
    }
}

// ---------------- kernel 2: binarize weights into MFMA B-fragment layout ----
__global__ __launch_bounds__(256) void pack_w(const float* __restrict__ wt,
                                              char* __restrict__ wB,
                                              float* __restrict__ scaleg) {
    __shared__ double red[256];
    int o = blockIdx.x, tid = threadIdx.x;
    const float* wo = wt + (size_t)o * 2304;

    double s = 0;
    for (int j = tid; j < 2304; j += 256) s += (double)wo[j];
    red[tid] = s;
    __syncthreads();
    for (int k = 128; k > 0; k >>= 1) {
        if (tid < k) red[tid] += red[tid + k];
        __syncthreads();
    }
    double mean = red[0] / 2304.0;
    __syncthreads();

    double s2 = 0;
    for (int j = tid; j < 2304; j += 256) s2 += fabs((double)wo[j] - mean);
    red[tid] = s2;
    __syncthreads();
    for (int k = 128; k > 0; k >>= 1) {
        if (tid < k) red[tid] += red[tid + k];
        __syncthreads();
    }
    if (tid == 0) scaleg[o] = (float)(red[0] / 2304.0);

    if (tid < 144) {
        int kiter = tid >> 2, q = tid & 3;     // kiter 0..35, q = k-quad
        int tap = kiter >> 2, cb = kiter & 3;
        int kh = tap / 3, kw = tap - kh * 3;
        int words[4];
        for (int g = 0; g < 4; ++g) {
            int word = 0;
            for (int b = 0; b < 4; ++b) {
                int c = cb * 64 + q * 16 + g * 4 + b;
                double v = (double)wo[c * 9 + kh * 3 + kw];
                int sg = (v > mean) - (v < mean);
                word |= (sg & 0xff) << (8 * b);
            }
            words[g] = word;
        }
        v4i pk = {words[0], words[1], words[2], words[3]};
        *(v4i*)(wB + (((size_t)kiter * 16 + (o >> 4)) * 64 + q * 16 + (o & 15)) * 16) = pk;
    }
}

// ---------------- kernel 3: i8 MFMA implicit-GEMM conv ----------------------
// block = (row-pair hp, n), 512 threads = 8 waves: 4 o-groups x 2 m-groups.
// Each wave: o = og*64 (4 o-frags), m-group 0 -> m-frags 0..3 (m 0..63),
//            m-group 1 -> m-frags 0..2 (m 64..111). K = 36 iters of 64.
template<int NMF>
__device__ __forceinline__ void conv_work(const char* xs, const v4i* wBw,
                                          int mbase, int lm, int q,
                                          int og, int n, int h0,
                                          const float* __restrict__ scaleg,
                                          float* __restrict__ out) {
    int wof[NMF], ro[NMF];
#pragma unroll
    for (int mf = 0; mf < NMF; ++mf) {
        int m = mbase + mf * 16 + lm;
        int r = (m >= 56) ? 1 : 0;
        ro[mf]  = r;
        wof[mf] = m - 56 * r;
    }

    v4i acc[NMF][4];
#pragma unroll
    for (int mf = 0; mf < NMF; ++mf)
#pragma unroll
        for (int of = 0; of < 4; ++of) { v4i z = {0, 0, 0, 0}; acc[mf][of] = z; }

    v4i bA[4], bB[4];
#pragma unroll
    for (int of = 0; of < 4; ++of) bA[of] = wBw[of * 64];

    for (int k2 = 0; k2 < 18; ++k2) {
        int k0 = 2 * k2, k1 = k0 + 1;
        // prefetch b(k1)
#pragma unroll
        for (int of = 0; of < 4; ++of) bB[of] = wBw[(size_t)k1 * 1024 + of * 64];
        // a(k0) jit + MFMA
        {
            int tap = k0 >> 2, cb = k0 & 3;
            int dh = tap / 3, dw = tap - dh * 3;
            int cbq = cb * 4 + q;
            v4i a[NMF];
#pragma unroll
            for (int mf = 0; mf < NMF; ++mf) {
                int win  = wof[mf] + dw;
                int pos  = (dh + ro[mf]) * 58 + win;
                int phys = (pos << 4) | ((cbq + win) & 15);
                a[mf] = *(const v4i*)(xs + ((size_t)phys << 4));
            }
            __builtin_amdgcn_s_setprio(1);
#pragma unroll
            for (int mf = 0; mf < NMF; ++mf)
#pragma unroll
                for (int of = 0; of < 4; ++of)
                    acc[mf][of] = __builtin_amdgcn_mfma_i32_16x16x64_i8(
                        a[mf], bA[of], acc[mf][of], 0, 0, 0);
            __builtin_amdgcn_s_setprio(0);
        }
        // prefetch b(k0+2)
        if (k2 < 17) {
#pragma unroll
            for (int of = 0; of < 4; ++of) bA[of] = wBw[(size_t)(k0 + 2) * 1024 + of * 64];
        }
        // a(k1) jit + MFMA
        {
            int tap = k1 >> 2, cb = k1 & 3;
            int dh = tap / 3, dw = tap - dh * 3;
            int cbq = cb * 4 + q;
            v4i a[NMF];
#pragma unroll
            for (int mf = 0; mf < NMF; ++mf) {
                int win  = wof[mf] + dw;
                int pos  = (dh + ro[mf]) * 58 + win;
                int phys = (pos << 4) | ((cbq + win) & 15);
                a[mf] = *(const v4i*)(xs + ((size_t)phys << 4));
            }
            __builtin_amdgcn_s_setprio(1);
#pragma unroll
            for (int mf = 0; mf < NMF; ++mf)
#pragma unroll
                for (int of = 0; of < 4; ++of)
                    acc[mf][of] = __builtin_amdgcn_mfma_i32_16x16x64_i8(
                        a[mf], bB[of], acc[mf][of], 0, 0, 0);
            __builtin_amdgcn_s_setprio(0);
        }
    }

    // epilogue: m = mbase + mf*16 + q*4 + reg; row split at m=56 is float4-aligned
#pragma unroll
    for (int of = 0; of < 4; ++of) {
        int o = og * 64 + of * 16 + lm;
        float s = scaleg[o];
#pragma unroll
        for (int mf = 0; mf < NMF; ++mf) {
            int m  = mbase + mf * 16 + q * 4;
            int r  = (m >= 56) ? 1 : 0;
            int wb = m - 56 * r;
            float* ob = out + ((size_t)(n * C_ + o) * H_ + h0 + r) * W_ + wb;
            float4 v = {s * (float)acc[mf][of].x, s * (float)acc[mf][of].y,
                        s * (float)acc[mf][of].z, s * (float)acc[mf][of].w};
            *(float4*)ob = v;
        }
    }
}

__global__ __launch_bounds__(512, 4) void conv_mfma(const char* __restrict__ sx,
                                                    const v4i* __restrict__ wB,
                                                    const float* __restrict__ scaleg,
                                                    float* __restrict__ out) {
    __shared__ char xs[4 * 58 * 256];   // 59,392 B -> 2 blocks/CU (118.8/160 KB)
    int tid = threadIdx.x;
    int wave = tid >> 6, lane = tid & 63;
    int hp = blockIdx.x, n = blockIdx.y;
    int h0 = hp * 2;

    // stage 4 padded rows (sx rows h0..h0+3), linear copy (swizzle pre-baked)
    const char* src = sx + ((size_t)n * 58 + h0) * (68 * 256);
    for (int i = tid; i < 4 * 58 * 16; i += 512) {
        int pos = i >> 4;                    // row*58 + w
        int row = pos / 58;
        int w   = pos - row * 58;
        v4i v = *(const v4i*)(src + ((size_t)(row * 68 + w) << 8) + ((size_t)(i & 15) << 4));
        *(v4i*)(xs + (size_t)i * 16) = v;
    }

    int lm = lane & 15, q = lane >> 4;
    int og = wave & 3;                       // o-group (64 outputs)
    int mg = wave >> 2;                      // m-group (0: m 0..63, 1: m 64..111)

    const v4i* wBw = wB + (size_t)(og * 4) * 64 + lane;   // + k*1024 + of*64

    __syncthreads();

    if (mg == 0)
        conv_work<4>(xs, wBw, 0,  lane & 15, lane >> 4, og, n, h0, scaleg, out);
    else
        conv_work<3>(xs, wBw, 64, lane & 15, lane >> 4, og, n, h0, scaleg, out);
    (void)lm; (void)q;
}

extern "C" void kernel_launch(void* const* d_in, const int* in_sizes, int n_in,
                              void* d_out, int out_size, void* d_ws, size_t ws_size,
                              hipStream_t stream) {
    const float* x   = (const float*)d_in[0];
    const float* wgt = (const float*)d_in[1];
    float* out = (float*)d_out;
    char* ws = (char*)d_ws;

    char*  sx = ws;
    char*  wb = ws + WB_OFF;
    float* sg = (float*)(ws + SC_OFF);

    zero_halo<<<dim3(58, N_), dim3(256), 0, stream>>>(sx);
    pack_x<<<dim3(49, N_), dim3(256), 0, stream>>>(x, sx);
    pack_w<<<dim3(256), dim3(256), 0, stream>>>(wgt, wb, sg);
    conv_mfma<<<dim3(28, N_), dim3(512), 0, stream>>>(sx, (const v4i*)wb, sg, out);
}

// Round 3
// 251.787 us; speedup vs baseline: 1.0435x; 1.0435x over previous
//
#include <hip/hip_runtime.h>
#include <cstdint>
#include <cstddef>

#define N_ 32
#define C_ 256
#define H_ 56
#define W_ 56

typedef int v4i __attribute__((ext_vector_type(4)));
typedef uint32_t __attribute__((address_space(1))) glb_u32;
typedef uint32_t __attribute__((address_space(3))) lds_u32;

// ---- workspace layout ----
// sx: padded sign-activations, i8, [n][58 rows][68 w][256 c], chunk-swizzled:
//     16B-chunk ch of position (row,w) lives at slot (ch + w) & 15.
static constexpr size_t SX_BYTES = (size_t)N_ * 58 * 68 * 256;   // 32,309,248
static constexpr size_t WB_OFF   = SX_BYTES;
static constexpr size_t WB_BYTES = 36ull * 16 * 64 * 16;         // 589,824
static constexpr size_t SC_OFF   = WB_OFF + WB_BYTES;            // 256 floats

// ---------------- kernel 1: pack x signs -> NHWC i8 (padded, pre-swizzled) ----
// bx 0..48: pack 64-hw tile x 256 channels. bx 49: zero halo rows. bx 50: halo cols.
__global__ __launch_bounds__(256) void pack_x(const float* __restrict__ x,
                                              char* __restrict__ sx) {
    int tid = threadIdx.x;
    int n   = blockIdx.y;
    v4i z = {0, 0, 0, 0};

    if (blockIdx.x >= 49) {
        if (blockIdx.x == 49) {
            // rows 0 and 57, w 0..57
            for (int i = tid; i < 2 * 58 * 16; i += 256) {
                int r   = i / (58 * 16);
                int rem = i - r * (58 * 16);
                char* base = sx + ((size_t)n * 58 + (size_t)r * 57) * (68 * 256);
                *(v4i*)(base + (size_t)rem * 16) = z;
            }
        } else {
            // cols w=0,57 of rows 1..56 (zeros are swizzle-invariant)
            for (int i = tid; i < 56 * 32; i += 256) {
                int r = 1 + (i >> 5);
                int c = i & 31;
                int wpos = (c >> 4) * 57, ch = c & 15;
                *(v4i*)(sx + (((size_t)n * 58 + r) * 68 + wpos) * 256 + ch * 16) = z;
            }
        }
        return;
    }

    __shared__ float tile[64 * 65];     // 16.6 KB
    __shared__ char  ob[64 * 256];      // 16 KB packed output tile
    int hw0 = blockIdx.x * 64;          // 49 tiles cover 3136 exactly

    int c16 = tid >> 4, hw4 = tid & 15;     // load-stage mapping (float4)
    int hwl2 = tid >> 2, cq  = tid & 3;     // pack-stage mapping

    for (int cb = 0; cb < 4; ++cb) {
        const float* xb = x + ((size_t)n * C_ + cb * 64) * 3136 + hw0;
#pragma unroll
        for (int j = 0; j < 4; ++j) {
            int cloc = j * 16 + c16;
            float4 v = *(const float4*)(xb + (size_t)cloc * 3136 + hw4 * 4);
            tile[cloc * 65 + hw4 * 4 + 0] = v.x;
            tile[cloc * 65 + hw4 * 4 + 1] = v.y;
            tile[cloc * 65 + hw4 * 4 + 2] = v.z;
            tile[cloc * 65 + hw4 * 4 + 3] = v.w;
        }
        __syncthreads();
        int words[4];
#pragma unroll
        for (int g = 0; g < 4; ++g) {
            int word = 0;
#pragma unroll
            for (int b = 0; b < 4; ++b) {
                float v = tile[(cq * 16 + g * 4 + b) * 65 + hwl2];
                int s = (v > 0.0f) - (v < 0.0f);    // exact sign, 0 at 0
                word |= (s & 0xff) << (8 * b);
            }
            words[g] = word;
        }
        v4i o4 = {words[0], words[1], words[2], words[3]};
        int ch   = cb * 4 + cq;                 // output 16B-chunk index 0..15
        int slot = (ch + hwl2) & 15;            // LDS-side rotation (bank spread)
        *(v4i*)(ob + hwl2 * 256 + slot * 16) = o4;
        __syncthreads();
    }

    // copy-out: contiguous full 256B lines; apply GLOBAL swizzle slot=(ch+wpad)&15
#pragma unroll
    for (int j = 0; j < 4; ++j) {
        int i = tid + j * 256;                  // 0..1023 chunk index in tile
        int hwl3 = i >> 4, ch = i & 15;
        v4i v = *(const v4i*)(ob + hwl3 * 256 + ((ch + hwl3) & 15) * 16);
        int hw = hw0 + hwl3;
        int h = hw / 56, w = hw - h * 56;
        int slot = (ch + (w + 1)) & 15;         // pre-swizzle on padded w index
        *(v4i*)(sx + (((size_t)n * 58 + h + 1) * 68 + (w + 1)) * 256 + slot * 16) = v;
    }
}

// ---------------- kernel 2: binarize weights into MFMA B-fragment layout ----
__global__ __launch_bounds__(256) void pack_w(const float* __restrict__ wt,
                                              char* __restrict__ wB,
                                              float* __restrict__ scaleg) {
    __shared__ double red[256];
    int o = blockIdx.x, tid = threadIdx.x;
    const float* wo = wt + (size_t)o * 2304;

    double s = 0;
    for (int j = tid; j < 2304; j += 256) s += (double)wo[j];
    red[tid] = s;
    __syncthreads();
    for (int k = 128; k > 0; k >>= 1) {
        if (tid < k) red[tid] += red[tid + k];
        __syncthreads();
    }
    double mean = red[0] / 2304.0;
    __syncthreads();

    double s2 = 0;
    for (int j = tid; j < 2304; j += 256) s2 += fabs((double)wo[j] - mean);
    red[tid] = s2;
    __syncthreads();
    for (int k = 128; k > 0; k >>= 1) {
        if (tid < k) red[tid] += red[tid + k];
        __syncthreads();
    }
    if (tid == 0) scaleg[o] = (float)(red[0] / 2304.0);

    if (tid < 144) {
        int kiter = tid >> 2, q = tid & 3;     // kiter 0..35, q = k-quad
        int tap = kiter >> 2, cb = kiter & 3;
        int kh = tap / 3, kw = tap - kh * 3;
        int words[4];
        for (int g = 0; g < 4; ++g) {
            int word = 0;
            for (int b = 0; b < 4; ++b) {
                int c = cb * 64 + q * 16 + g * 4 + b;
                double v = (double)wo[c * 9 + kh * 3 + kw];
                int sg = (v > mean) - (v < mean);
                word |= (sg & 0xff) << (8 * b);
            }
            words[g] = word;
        }
        v4i pk = {words[0], words[1], words[2], words[3]};
        *(v4i*)(wB + (((size_t)kiter * 16 + (o >> 4)) * 64 + q * 16 + (o & 15)) * 16) = pk;
    }
}

// ---------------- kernel 3: i8 MFMA implicit-GEMM conv, 4 rows/block ---------
// block = (row-quad hq, n): 14 x 32 = 448 blocks, 512 threads = 8 waves.
// Waves: og = wave&3 (64 outputs), mg = wave>>2 (m half: 112 each).
// m = mg*112 + mf*16 + lm -> row r = m/56, w = m%56. m total 224 = 14 frags.
// Per wave per k-iter: 7 mf x 4 of = 28 MFMAs. K = 36 iters of 64.
// Per-wave k-rotation (kstart = 9*wave/2) decorrelates L2/LDS bursts; i32
// accumulation is exact so k order is free.
__device__ __forceinline__ void stage_chunk(const char* src, char* xs, int i) {
    int pos = i >> 4;                        // row*58 + w, pos <= 347
    int row = (pos * 1130) >> 16;            // pos/58 (exact for pos<=347)
    int w   = pos - row * 58;
    const char* g = src + (((size_t)(row * 68 + w)) << 8) + ((size_t)(i & 15) << 4);
    char* l = xs + (size_t)i * 16;
    __builtin_amdgcn_global_load_lds((const glb_u32*)g, (lds_u32*)l, 16, 0, 0);
}

__global__ __launch_bounds__(512, 2) void conv_mfma(const char* __restrict__ sx,
                                                    const v4i* __restrict__ wB,
                                                    const float* __restrict__ scaleg,
                                                    float* __restrict__ out) {
    __shared__ char xs[6 * 58 * 256];   // 89,088 B -> 1 block/CU
    int tid = threadIdx.x;
    int wave = tid >> 6, lane = tid & 63;
    int hq = blockIdx.x, n = blockIdx.y;
    int h0 = hq * 4;

    // stage 6 padded rows (sx rows h0..h0+5) via async global->LDS, linear dest
    const char* src = sx + ((size_t)n * 58 + h0) * (68 * 256);
#pragma unroll
    for (int it = 0; it < 10; ++it) stage_chunk(src, xs, tid + it * 512);
    if (tid < 448) stage_chunk(src, xs, tid + 5120);   // 5568 = 10*512 + 448

    int lm = lane & 15, q = lane >> 4;
    int og = wave & 3, mg = wave >> 2;
    int kstart = __builtin_amdgcn_readfirstlane((9 * wave) >> 1);  // 0,4,9,13,18,22,27,31

    // per-m-frag geometry (lane-constant across k)
    int posb[7], slotb[7];
#pragma unroll
    for (int mf = 0; mf < 7; ++mf) {
        int m = mg * 112 + mf * 16 + lm;
        int r = m / 56;
        int wof = m - r * 56;
        posb[mf]  = r * 58 + wof;
        slotb[mf] = q + wof;
    }

    v4i acc[7][4];
#pragma unroll
    for (int mf = 0; mf < 7; ++mf)
#pragma unroll
        for (int of = 0; of < 4; ++of) { v4i z = {0, 0, 0, 0}; acc[mf][of] = z; }

    const v4i* wBw = wB + (size_t)(og * 4) * 64 + lane;   // + k*1024 + of*64

    __syncthreads();   // drains global_load_lds (vmcnt 0) before reads

    v4i bA[4], bB[4], aA[7], aB[7];

    auto loadB = [&](int k, v4i* b) {
#pragma unroll
        for (int of = 0; of < 4; ++of) b[of] = wBw[(size_t)k * 1024 + of * 64];
    };
    auto loadA = [&](int k, v4i* a) {
        int tap = k >> 2, cb = k & 3;
        int dh = (tap * 11) >> 5;            // tap/3 for tap<=8
        int dw = tap - dh * 3;
        int pofs = dh * 58 + dw;
        int sofs = cb * 4 + dw;
#pragma unroll
        for (int mf = 0; mf < 7; ++mf) {
            int pos  = posb[mf] + pofs;
            int slot = (slotb[mf] + sofs) & 15;
            a[mf] = *(const v4i*)(xs + ((size_t)pos << 8) + ((size_t)slot << 4));
        }
    };
    auto wrap = [&](int t) { int k = kstart + t; return k >= 36 ? k - 36 : k; };

    // prologue
    loadB(kstart, bA);
    loadA(kstart, aA);

    for (int t2 = 0; t2 < 18; ++t2) {
        int ta = 2 * t2;
        // prefetch (ta+1)
        {
            int kb = wrap(ta + 1);
            loadB(kb, bB);
            loadA(kb, aB);
        }
        __builtin_amdgcn_s_setprio(1);
#pragma unroll
        for (int mf = 0; mf < 7; ++mf)
#pragma unroll
            for (int of = 0; of < 4; ++of)
                acc[mf][of] = __builtin_amdgcn_mfma_i32_16x16x64_i8(
                    aA[mf], bA[of], acc[mf][of], 0, 0, 0);
        __builtin_amdgcn_s_setprio(0);
        // prefetch (ta+2)
        if (t2 < 17) {
            int kc = wrap(ta + 2);
            loadB(kc, bA);
            loadA(kc, aA);
        }
        __builtin_amdgcn_s_setprio(1);
#pragma unroll
        for (int mf = 0; mf < 7; ++mf)
#pragma unroll
            for (int of = 0; of < 4; ++of)
                acc[mf][of] = __builtin_amdgcn_mfma_i32_16x16x64_i8(
                    aB[mf], bB[of], acc[mf][of], 0, 0, 0);
        __builtin_amdgcn_s_setprio(0);
    }

    // epilogue: m = mg*112 + mf*16 + q*4 + reg; r = m/56 (float4-aligned), w = m%56
#pragma unroll
    for (int of = 0; of < 4; ++of) {
        int o = og * 64 + of * 16 + lm;
        float s = scaleg[o];
#pragma unroll
        for (int mf = 0; mf < 7; ++mf) {
            int m  = mg * 112 + mf * 16 + q * 4;
            int r  = m / 56;
            int wb = m - r * 56;
            float* ob = out + ((size_t)(n * C_ + o) * H_ + h0 + r) * W_ + wb;
            float4 v = {s * (float)acc[mf][of].x, s * (float)acc[mf][of].y,
                        s * (float)acc[mf][of].z, s * (float)acc[mf][of].w};
            *(float4*)ob = v;
        }
    }
}

extern "C" void kernel_launch(void* const* d_in, const int* in_sizes, int n_in,
                              void* d_out, int out_size, void* d_ws, size_t ws_size,
                              hipStream_t stream) {
    const float* x   = (const float*)d_in[0];
    const float* wgt = (const float*)d_in[1];
    float* out = (float*)d_out;
    char* ws = (char*)d_ws;

    char*  sx = ws;
    char*  wb = ws + WB_OFF;
    float* sg = (float*)(ws + SC_OFF);

    pack_x<<<dim3(51, N_), dim3(256), 0, stream>>>(x, sx);
    pack_w<<<dim3(256), dim3(256), 0, stream>>>(wgt, wb, sg);
    conv_mfma<<<dim3(14, N_), dim3(512), 0, stream>>>(sx, (const v4i*)wb, sg, out);
}